// Round 8
// baseline (170.831 us; speedup 1.0000x reference)
//
#include <hip/hip_runtime.h>
#include <hip/hip_bf16.h>

// Problem constants: B=4, L=2048, H=8, D=64, SAMPLE_K=N_TOP=40
#define BB 4
#define LL 2048
#define HH 8
#define DD 64
#define SK 40
#define NT 40
#define CH 256              // keys per attn chunk
#define NCH (LL / CH)       // 8 chunks per (b,h)
#define QH 20               // queries per attn block (40 split in 2)

typedef float f4 __attribute__((ext_vector_type(4)));

// ---------------------------------------------------------------------------
// Kernel 1: M[bh][l] = max_s(q . k_{idx[l,s]}) - (sum_s q . k_{idx[l,s]}) / L
//
// Round 21: ONE WAVE = ONE (b,l), all 40 samples. Previous structures gave a
// wave only 10 samples: ~600-900cy idx->addr->K startup chain + 5-step drain
// tail amortized over 10 consumes, x4 waves + block barrier + LDS merge ->
// every variant stuck at 41-46us vs the ~17us L1-line-service floor.
// This version: grid 2048 blocks, wave w owns l = lg*4+w. Per wave:
//  - idx row (40 ints) loaded once by lanes 0..39, broadcast via readlane
//    into SGPRs -> K loads use saddr form (global_load_dwordx4 v,voff,s[b])
//    with scalar address arithmetic (VALU stays free for FMAs);
//  - 40-sample rolling pipeline, 8 rotating register pairs, 16 loads in
//    flight steady-state (s_waitcnt vmcnt(14)), tail drains 14..0;
//  - whole-wave-per-row layout (round 19): lane's floats [lane*8,+8) of the
//    2KB row = head lane>>3, dims 8*(lane&7)..+7; Q fragment at the SAME
//    offset (identity map). 8 FMAs + 3 shfl_xor per sample, 8-lane groups.
//  - NO LDS, NO __syncthreads; 8 group leaders store M directly.
// ---------------------------------------------------------------------------
__global__ __launch_bounds__(256, 4) void compute_m_kernel(
        const float* __restrict__ Q, const float* __restrict__ K,
        const int* __restrict__ idx, float* __restrict__ M) {
    int blk = blockIdx.x;
    int x = blk & 7, g = blk >> 3;
    int b = x >> 1;                    // XCD pair -> batch (per-batch K ~4.2MB ~ XCD L2)
    int lg = (g << 1) | (x & 1);       // l-group [0,512)
    int t = threadIdx.x;
    int lane = t & 63, w = t >> 6;
    int l = lg * 4 + w;                // this wave's l
    int grp = lane >> 3;               // head this lane contributes to

    // Q fragment: identity map — floats [lane*8, +8) of row l
    const float* Qrow = Q + ((size_t)b * LL + l) * 512 + lane * 8;
    f4 qa = *(const f4*)(Qrow);
    f4 qb = *(const f4*)(Qrow + 4);

    // idx row: one coalesced 160B read by lanes 0..39, then readlane-broadcast
    int myidx = 0;
    if (lane < SK) myidx = idx[(size_t)l * SK + lane];

    const float* Kb8 = K + (size_t)b * LL * 512;   // uniform base (lane off in voff)
    int voff = lane * 32;                          // byte offset of lane's 32B fragment

    // Drain compiler-tracked loads (Q) before the asm pipeline.
    asm volatile("" : "+v"(qa), "+v"(qb));

    f4 A0, B0, A1, B1, A2, B2, A3, B3, A4, B4, A5, B5, A6, B6, A7, B7;

    #define PTRK(k) (Kb8 + (size_t)__builtin_amdgcn_readlane(myidx, (k)) * 512)
    #define IS(AV, BV, k)                                                       \
        asm volatile("global_load_dwordx4 %0, %2, %3\n\t"                       \
                     "global_load_dwordx4 %1, %2, %3 offset:16"                 \
                     : "=&v"(AV), "=&v"(BV) : "v"(voff), "s"(PTRK(k)))

    float mx = -INFINITY, sm = 0.0f;

    #define CO(AV, BV, WAIT) do {                                               \
        asm volatile(WAIT : "+v"(AV), "+v"(BV));                                \
        float p = qa.x*AV.x + qa.y*AV.y + qa.z*AV.z + qa.w*AV.w                 \
                + qb.x*BV.x + qb.y*BV.y + qb.z*BV.z + qb.w*BV.w;                \
        p += __shfl_xor(p, 1, 64);                                              \
        p += __shfl_xor(p, 2, 64);                                              \
        p += __shfl_xor(p, 4, 64);                                              \
        mx = fmaxf(mx, p);                                                      \
        sm += p;                                                                \
    } while (0)

    // prologue: fill 8 pairs (16 loads in flight)
    IS(A0, B0, 0); IS(A1, B1, 1); IS(A2, B2, 2); IS(A3, B3, 3);
    IS(A4, B4, 4); IS(A5, B5, 5); IS(A6, B6, 6); IS(A7, B7, 7);
    // steady state: consume oldest pair, refill with sample k+8
    CO(A0, B0, "s_waitcnt vmcnt(14)"); IS(A0, B0,  8);
    CO(A1, B1, "s_waitcnt vmcnt(14)"); IS(A1, B1,  9);
    CO(A2, B2, "s_waitcnt vmcnt(14)"); IS(A2, B2, 10);
    CO(A3, B3, "s_waitcnt vmcnt(14)"); IS(A3, B3, 11);
    CO(A4, B4, "s_waitcnt vmcnt(14)"); IS(A4, B4, 12);
    CO(A5, B5, "s_waitcnt vmcnt(14)"); IS(A5, B5, 13);
    CO(A6, B6, "s_waitcnt vmcnt(14)"); IS(A6, B6, 14);
    CO(A7, B7, "s_waitcnt vmcnt(14)"); IS(A7, B7, 15);
    CO(A0, B0, "s_waitcnt vmcnt(14)"); IS(A0, B0, 16);
    CO(A1, B1, "s_waitcnt vmcnt(14)"); IS(A1, B1, 17);
    CO(A2, B2, "s_waitcnt vmcnt(14)"); IS(A2, B2, 18);
    CO(A3, B3, "s_waitcnt vmcnt(14)"); IS(A3, B3, 19);
    CO(A4, B4, "s_waitcnt vmcnt(14)"); IS(A4, B4, 20);
    CO(A5, B5, "s_waitcnt vmcnt(14)"); IS(A5, B5, 21);
    CO(A6, B6, "s_waitcnt vmcnt(14)"); IS(A6, B6, 22);
    CO(A7, B7, "s_waitcnt vmcnt(14)"); IS(A7, B7, 23);
    CO(A0, B0, "s_waitcnt vmcnt(14)"); IS(A0, B0, 24);
    CO(A1, B1, "s_waitcnt vmcnt(14)"); IS(A1, B1, 25);
    CO(A2, B2, "s_waitcnt vmcnt(14)"); IS(A2, B2, 26);
    CO(A3, B3, "s_waitcnt vmcnt(14)"); IS(A3, B3, 27);
    CO(A4, B4, "s_waitcnt vmcnt(14)"); IS(A4, B4, 28);
    CO(A5, B5, "s_waitcnt vmcnt(14)"); IS(A5, B5, 29);
    CO(A6, B6, "s_waitcnt vmcnt(14)"); IS(A6, B6, 30);
    CO(A7, B7, "s_waitcnt vmcnt(14)"); IS(A7, B7, 31);
    CO(A0, B0, "s_waitcnt vmcnt(14)"); IS(A0, B0, 32);
    CO(A1, B1, "s_waitcnt vmcnt(14)"); IS(A1, B1, 33);
    CO(A2, B2, "s_waitcnt vmcnt(14)"); IS(A2, B2, 34);
    CO(A3, B3, "s_waitcnt vmcnt(14)"); IS(A3, B3, 35);
    CO(A4, B4, "s_waitcnt vmcnt(14)"); IS(A4, B4, 36);
    CO(A5, B5, "s_waitcnt vmcnt(14)"); IS(A5, B5, 37);
    CO(A6, B6, "s_waitcnt vmcnt(14)"); IS(A6, B6, 38);
    CO(A7, B7, "s_waitcnt vmcnt(14)"); IS(A7, B7, 39);
    // tail drain
    CO(A0, B0, "s_waitcnt vmcnt(14)");
    CO(A1, B1, "s_waitcnt vmcnt(12)");
    CO(A2, B2, "s_waitcnt vmcnt(10)");
    CO(A3, B3, "s_waitcnt vmcnt(8)");
    CO(A4, B4, "s_waitcnt vmcnt(6)");
    CO(A5, B5, "s_waitcnt vmcnt(4)");
    CO(A6, B6, "s_waitcnt vmcnt(2)");
    CO(A7, B7, "s_waitcnt vmcnt(0)");
    #undef IS
    #undef CO
    #undef PTRK

    // group leader (lane = grp*8) holds head grp's (mx, sm) for this l
    if ((lane & 7) == 0)
        M[((size_t)b * HH + grp) * LL + l] = mx - sm * (1.0f / (float)LL);
}

// ---------------------------------------------------------------------------
// Kernel 2: top-40 per (b,h), lower index wins ties. Incremental argmax.
// ---------------------------------------------------------------------------
__global__ __launch_bounds__(256) void topk_kernel(const float* __restrict__ M,
                                                   int* __restrict__ topi) {
    __shared__ unsigned long long keys[LL];   // 16 KB
    __shared__ unsigned long long wmax[4];
    __shared__ int win;
    int bh = blockIdx.x;
    int t  = threadIdx.x;
    int lane = t & 63, w = t >> 6;

    unsigned long long kmax = 0ULL;
    #pragma unroll
    for (int j = 0; j < 8; ++j) {
        int i = t + 256 * j;
        unsigned int bits = __float_as_uint(M[(size_t)bh * LL + i]);
        bits = (bits & 0x80000000u) ? ~bits : (bits | 0x80000000u);
        unsigned long long k = ((unsigned long long)bits << 11)
                             | (unsigned int)(LL - 1 - i);
        keys[i] = k;
        if (k > kmax) kmax = k;
    }
    __syncthreads();

    for (int u = 0; u < NT; ++u) {
        unsigned long long k = kmax;
        #pragma unroll
        for (int off = 32; off >= 1; off >>= 1) {
            unsigned long long o = __shfl_xor(k, off, 64);
            if (o > k) k = o;
        }
        if (lane == 0) wmax[w] = k;
        __syncthreads();
        if (t == 0) {
            unsigned long long k0 = wmax[0];
            if (wmax[1] > k0) k0 = wmax[1];
            if (wmax[2] > k0) k0 = wmax[2];
            if (wmax[3] > k0) k0 = wmax[3];
            int i = (LL - 1) - (int)(k0 & 0x7FF);
            topi[bh * NT + u] = i;
            keys[i] = 0ULL;
            win = i;
        }
        __syncthreads();
        if ((win & 255) == t) {          // only the owner rescans
            kmax = 0ULL;
            #pragma unroll
            for (int j = 0; j < 8; ++j) {
                unsigned long long kk = keys[t + 256 * j];
                if (kk > kmax) kmax = kk;
            }
        }
    }
}

// ---------------------------------------------------------------------------
// Kernel 3: flash-chunked attention, query-split.
// __launch_bounds__(256,3) keeps kreg/vcol in registers (round 7 spill fix).
// (m,l) packed float2 store (round 8 granule-waste fix).
// ---------------------------------------------------------------------------
__global__ __launch_bounds__(256, 3) void attn_kernel(
        const float* __restrict__ Q, const float* __restrict__ K,
        const float* __restrict__ V, const int* __restrict__ topi,
        float2* __restrict__ pml, float* __restrict__ po) {
    __shared__ float  qs[QH][DD];        //  5120 B
    __shared__ float4 e4buf[4][64];      //  4096 B
    __shared__ float  oarea[4][QH][DD];  // 20480 B
    __shared__ float  mlarea[4][QH][2];  //   640 B

    int blk = blockIdx.x;
    int qh  = blk >> 8;                  // 0/1 query half
    int cc2 = blk & 255;
    int c   = cc2 & (NCH - 1);
    int bh  = cc2 >> 3;
    int h = bh & (HH - 1), b = bh >> 3;
    int t = threadIdx.x, lane = t & 63, w = t >> 6;
    int u0 = qh * QH;

    for (int i = t; i < QH * DD; i += 256) {
        int u = i >> 6, d = i & 63;
        int lq = topi[bh * NT + u0 + u];
        qs[u][d] = Q[(((size_t)b * LL + lq) * HH + h) * DD + d];
    }

    int key = c * CH + w * 64 + lane;
    const float4* kr = (const float4*)&K[(((size_t)b * LL + key) * HH + h) * DD];
    float4 kreg[16];
    #pragma unroll
    for (int j = 0; j < 16; ++j) kreg[j] = kr[j];

    float vcol[64];
    const float* vb = &V[(((size_t)b * LL + c * CH + w * 64) * HH + h) * DD + lane];
    #pragma unroll
    for (int j = 0; j < 64; ++j) vcol[j] = vb[(size_t)j * HH * DD];

    __syncthreads();   // qs ready

    for (int uq = 0; uq < QH / 4; ++uq) {
        float o0 = 0, o1 = 0, o2 = 0, o3 = 0;
        float mv0, mv1, mv2, mv3, lv0, lv1, lv2, lv3;
        float4 ev;
        #pragma unroll
        for (int j = 0; j < 4; ++j) {
            int u = uq * 4 + j;
            const float4* q4 = (const float4*)&qs[u][0];
            float s = 0.0f;
            #pragma unroll
            for (int cc = 0; cc < 16; ++cc) {
                float4 qv = q4[cc];
                s += qv.x * kreg[cc].x + qv.y * kreg[cc].y
                   + qv.z * kreg[cc].z + qv.w * kreg[cc].w;
            }
            s *= 0.125f;   // 1/sqrt(64)
            float m = s;
            #pragma unroll
            for (int off = 32; off >= 1; off >>= 1)
                m = fmaxf(m, __shfl_xor(m, off, 64));
            float e = __expf(s - m);
            float ls = e;
            #pragma unroll
            for (int off = 32; off >= 1; off >>= 1)
                ls += __shfl_xor(ls, off, 64);
            if (j == 0) { mv0 = m; lv0 = ls; ev.x = e; }
            if (j == 1) { mv1 = m; lv1 = ls; ev.y = e; }
            if (j == 2) { mv2 = m; lv2 = ls; ev.z = e; }
            if (j == 3) { mv3 = m; lv3 = ls; ev.w = e; }
        }
        e4buf[w][lane] = ev;
        asm volatile("s_waitcnt lgkmcnt(0)" ::: "memory");
        #pragma unroll
        for (int l2 = 0; l2 < 64; ++l2) {      // FULL unroll: vcol static
            float4 e = e4buf[w][l2];
            float  v = vcol[l2];
            o0 += e.x * v; o1 += e.y * v; o2 += e.z * v; o3 += e.w * v;
        }
        oarea[w][uq * 4 + 0][lane] = o0;
        oarea[w][uq * 4 + 1][lane] = o1;
        oarea[w][uq * 4 + 2][lane] = o2;
        oarea[w][uq * 4 + 3][lane] = o3;
        if (lane == 0) {
            mlarea[w][uq * 4 + 0][0] = mv0; mlarea[w][uq * 4 + 0][1] = lv0;
            mlarea[w][uq * 4 + 1][0] = mv1; mlarea[w][uq * 4 + 1][1] = lv1;
            mlarea[w][uq * 4 + 2][0] = mv2; mlarea[w][uq * 4 + 2][1] = lv2;
            mlarea[w][uq * 4 + 3][0] = mv3; mlarea[w][uq * 4 + 3][1] = lv3;
        }
    }
    __syncthreads();

    for (int i = t; i < QH * DD; i += 256) {
        int u = i >> 6, d = i & 63;
        float m0 = mlarea[0][u][0], m1 = mlarea[1][u][0];
        float m2 = mlarea[2][u][0], m3 = mlarea[3][u][0];
        float mb = fmaxf(fmaxf(m0, m1), fmaxf(m2, m3));
        float s0 = __expf(m0 - mb), s1 = __expf(m1 - mb);
        float s2 = __expf(m2 - mb), s3 = __expf(m3 - mb);
        float ob = oarea[0][u][d] * s0 + oarea[1][u][d] * s1
                 + oarea[2][u][d] * s2 + oarea[3][u][d] * s3;
        int gu = u0 + u;
        po[((size_t)(bh * NT + gu) * NCH + c) * DD + d] = ob;
        if (d == 0) {
            float lb = mlarea[0][u][1] * s0 + mlarea[1][u][1] * s1
                     + mlarea[2][u][1] * s2 + mlarea[3][u][1] * s3;
            pml[(bh * NT + gu) * NCH + c] = make_float2(mb, lb);
        }
    }
}

// ---------------------------------------------------------------------------
// Kernel 4: merge chunk partials. One wave per (bh,u), lane = d.
// ---------------------------------------------------------------------------
__global__ __launch_bounds__(256) void merge_kernel(
        const float2* __restrict__ pml, const float* __restrict__ po,
        float* __restrict__ out) {
    int wid  = blockIdx.x * 4 + (threadIdx.x >> 6);
    int lane = threadIdx.x & 63;
    int u  = wid % NT;
    int bh = wid / NT;
    int h = bh & (HH - 1), b = bh >> 3;
    int base = (bh * NT + u) * NCH;

    float m = -INFINITY;
    #pragma unroll
    for (int cc = 0; cc < NCH; ++cc) m = fmaxf(m, pml[base + cc].x);
    float lsum = 0.0f, o = 0.0f;
    #pragma unroll
    for (int cc = 0; cc < NCH; ++cc) {
        float2 ml = pml[base + cc];
        float sc = __expf(ml.x - m);
        lsum += ml.y * sc;
        o    += po[(size_t)(base + cc) * DD + lane] * sc;
    }
    out[(((size_t)b * NT + u) * HH + h) * DD + lane] = o / lsum;
}

extern "C" void kernel_launch(void* const* d_in, const int* in_sizes, int n_in,
                              void* d_out, int out_size, void* d_ws, size_t ws_size,
                              hipStream_t stream) {
    const float* Q   = (const float*)d_in[0];
    const float* K   = (const float*)d_in[1];
    const float* V   = (const float*)d_in[2];
    const int*   idx = (const int*)d_in[3];
    float* out = (float*)d_out;

    char* ws = (char*)d_ws;
    float*  M    = (float*)ws;                        ws += (size_t)BB * HH * LL * sizeof(float);
    int*    topi = (int*)ws;                          ws += (size_t)BB * HH * NT * sizeof(int);
    float2* pml  = (float2*)ws;                       ws += (size_t)BB * HH * NT * NCH * sizeof(float2);
    float*  po   = (float*)ws;                        // 2.62 MB

    hipLaunchKernelGGL(compute_m_kernel, dim3(BB * LL / 4), dim3(256), 0, stream,
                       Q, K, idx, M);
    hipLaunchKernelGGL(topk_kernel, dim3(BB * HH), dim3(256), 0, stream, M, topi);
    hipLaunchKernelGGL(attn_kernel, dim3(2 * BB * HH * NCH), dim3(256), 0, stream,
                       Q, K, V, topi, pml, po);
    hipLaunchKernelGGL(merge_kernel, dim3(BB * HH * NT / 4), dim3(256), 0, stream,
                       pml, po, out);
}